// Round 1
// baseline (2773.177 us; speedup 1.0000x reference)
//
#include <hip/hip_runtime.h>
#include <math.h>

#define TSEQ 4096
#define DMODEL 512
#define NHEADS 8
#define HD 64

// ---------------------------------------------------------------------------
// Projection: Y = X @ W^T + bias   (X:[M,512], W:[512,512] row-major, Y:[M,512])
// grid (M/64, 512/64, 3) ; block 256 ; 64x64 tile, 4x4 per thread, BK=32
// ---------------------------------------------------------------------------
__global__ __launch_bounds__(256) void proj_kernel(
    const float* __restrict__ X,
    const float* __restrict__ Wq, const float* __restrict__ bq,
    const float* __restrict__ Wk, const float* __restrict__ bk,
    const float* __restrict__ Wv, const float* __restrict__ bv,
    float* __restrict__ Qo, float* __restrict__ Ko, float* __restrict__ Vo)
{
    const int z = blockIdx.z;
    const float* __restrict__ W    = (z == 0) ? Wq : (z == 1) ? Wk : Wv;
    const float* __restrict__ bias = (z == 0) ? bq : (z == 1) ? bk : bv;
    float* __restrict__ Y          = (z == 0) ? Qo : (z == 1) ? Ko : Vo;

    const int m0 = blockIdx.x * 64;
    const int n0 = blockIdx.y * 64;
    const int tid = threadIdx.x;
    const int ty = tid >> 4;      // 0..15 -> rows ty*4..ty*4+3
    const int tx = tid & 15;      // 0..15 -> cols tx+16j

    // pitch 36 floats = 144 B (16B aligned rows; 36%32=4 -> conflict-free-ish)
    __shared__ float xs[64][36];
    __shared__ float ws[64][36];

    float acc[4][4] = {};

    for (int k0 = 0; k0 < DMODEL; k0 += 32) {
        #pragma unroll
        for (int rep = 0; rep < 2; ++rep) {
            int idx = rep * 256 + tid;
            int row = idx >> 3;          // 0..63
            int c4  = (idx & 7) * 4;     // 0..28
            *(float4*)&xs[row][c4] = *(const float4*)&X[(size_t)(m0 + row) * DMODEL + k0 + c4];
            *(float4*)&ws[row][c4] = *(const float4*)&W[(size_t)(n0 + row) * DMODEL + k0 + c4];
        }
        __syncthreads();
        #pragma unroll
        for (int kkb = 0; kkb < 8; ++kkb) {
            float4 a[4], bb[4];
            #pragma unroll
            for (int i = 0; i < 4; ++i) a[i]  = *(const float4*)&xs[ty * 4 + i][kkb * 4];
            #pragma unroll
            for (int j = 0; j < 4; ++j) bb[j] = *(const float4*)&ws[tx + 16 * j][kkb * 4];
            #pragma unroll
            for (int i = 0; i < 4; ++i)
                #pragma unroll
                for (int j = 0; j < 4; ++j)
                    acc[i][j] += a[i].x * bb[j].x + a[i].y * bb[j].y
                               + a[i].z * bb[j].z + a[i].w * bb[j].w;
        }
        __syncthreads();
    }

    #pragma unroll
    for (int j = 0; j < 4; ++j) {
        int n = n0 + tx + 16 * j;
        float bv_ = bias[n];
        #pragma unroll
        for (int i = 0; i < 4; ++i) {
            int m = m0 + ty * 4 + i;
            Y[(size_t)m * DMODEL + n] = acc[i][j] + bv_;
        }
    }
}

// ---------------------------------------------------------------------------
// Flash attention, reference semantics: scores = K @ Q^T (K rows = out rows),
// softmax over q, out = attn @ V.
// grid (T/64, H, B) ; block 256 ; 64 out-rows per block ; online softmax.
// ---------------------------------------------------------------------------
__global__ __launch_bounds__(256) void attn_kernel(
    const float* __restrict__ Qp, const float* __restrict__ Kp,
    const float* __restrict__ Vp, float* __restrict__ Out)
{
    const int b  = blockIdx.z;
    const int h  = blockIdx.y;
    const int r0 = blockIdx.x * 64;
    const int tid = threadIdx.x;
    const int ty = tid >> 4;
    const int tx = tid & 15;
    const int hoff = h * HD;
    const size_t base = (size_t)b * TSEQ * DMODEL;

    __shared__ float Ks[64][68];   // K rows (resident for the block)
    __shared__ float Qs[64][68];   // current q-tile
    __shared__ float Vt[64][68];   // V transposed: Vt[d][q]
    __shared__ float Ps[64][68];   // exp(scores)

    #pragma unroll
    for (int rep = 0; rep < 4; ++rep) {
        int idx = rep * 256 + tid;
        int row = idx >> 4;
        int c4  = (idx & 15) * 4;
        *(float4*)&Ks[row][c4] =
            *(const float4*)&Kp[base + (size_t)(r0 + row) * DMODEL + hoff + c4];
    }

    float m_i[4], l_i[4], acc[4][4] = {};
    #pragma unroll
    for (int i = 0; i < 4; ++i) { m_i[i] = -INFINITY; l_i[i] = 0.f; }

    for (int c0 = 0; c0 < TSEQ; c0 += 64) {
        #pragma unroll
        for (int rep = 0; rep < 4; ++rep) {
            int idx = rep * 256 + tid;
            int row = idx >> 4;
            int c4  = (idx & 15) * 4;
            *(float4*)&Qs[row][c4] =
                *(const float4*)&Qp[base + (size_t)(c0 + row) * DMODEL + hoff + c4];
            float4 v = *(const float4*)&Vp[base + (size_t)(c0 + row) * DMODEL + hoff + c4];
            Vt[c4 + 0][row] = v.x;
            Vt[c4 + 1][row] = v.y;
            Vt[c4 + 2][row] = v.z;
            Vt[c4 + 3][row] = v.w;
        }
        __syncthreads();

        // S = K_tile @ Q_tile^T  (4x4 per thread), rows ty*4+i, cols tx+16j
        float s[4][4] = {};
        #pragma unroll
        for (int kkb = 0; kkb < 16; ++kkb) {
            float4 a[4], q4[4];
            #pragma unroll
            for (int i = 0; i < 4; ++i) a[i]  = *(const float4*)&Ks[ty * 4 + i][kkb * 4];
            #pragma unroll
            for (int j = 0; j < 4; ++j) q4[j] = *(const float4*)&Qs[tx + 16 * j][kkb * 4];
            #pragma unroll
            for (int i = 0; i < 4; ++i)
                #pragma unroll
                for (int j = 0; j < 4; ++j)
                    s[i][j] += a[i].x * q4[j].x + a[i].y * q4[j].y
                             + a[i].z * q4[j].z + a[i].w * q4[j].w;
        }

        const float scale = 0.125f;  // 1/sqrt(64)
        float p[4][4];
        #pragma unroll
        for (int i = 0; i < 4; ++i) {
            float rm = -INFINITY;
            #pragma unroll
            for (int j = 0; j < 4; ++j) { s[i][j] *= scale; rm = fmaxf(rm, s[i][j]); }
            // reduce max across the 16-lane row group
            #pragma unroll
            for (int msk = 1; msk < 16; msk <<= 1)
                rm = fmaxf(rm, __shfl_xor(rm, msk));
            float nm = fmaxf(m_i[i], rm);
            float alpha = __expf(m_i[i] - nm);
            float rs = 0.f;
            #pragma unroll
            for (int j = 0; j < 4; ++j) { p[i][j] = __expf(s[i][j] - nm); rs += p[i][j]; }
            #pragma unroll
            for (int msk = 1; msk < 16; msk <<= 1)
                rs += __shfl_xor(rs, msk);
            m_i[i] = nm;
            l_i[i] = l_i[i] * alpha + rs;
            #pragma unroll
            for (int j = 0; j < 4; ++j) acc[i][j] *= alpha;
        }

        #pragma unroll
        for (int i = 0; i < 4; ++i)
            #pragma unroll
            for (int j = 0; j < 4; ++j)
                Ps[ty * 4 + i][tx + 16 * j] = p[i][j];
        __syncthreads();

        // acc += P @ V   (contiguous along q via Vt)
        #pragma unroll
        for (int qb = 0; qb < 16; ++qb) {
            float4 pp[4], vv[4];
            #pragma unroll
            for (int i = 0; i < 4; ++i) pp[i] = *(const float4*)&Ps[ty * 4 + i][qb * 4];
            #pragma unroll
            for (int j = 0; j < 4; ++j) vv[j] = *(const float4*)&Vt[tx + 16 * j][qb * 4];
            #pragma unroll
            for (int i = 0; i < 4; ++i)
                #pragma unroll
                for (int j = 0; j < 4; ++j)
                    acc[i][j] += pp[i].x * vv[j].x + pp[i].y * vv[j].y
                               + pp[i].z * vv[j].z + pp[i].w * vv[j].w;
        }
        __syncthreads();
    }

    #pragma unroll
    for (int i = 0; i < 4; ++i) {
        float inv = 1.f / l_i[i];
        #pragma unroll
        for (int j = 0; j < 4; ++j)
            Out[base + (size_t)(r0 + ty * 4 + i) * DMODEL + hoff + tx + 16 * j] =
                acc[i][j] * inv;
    }
}

// ---------------------------------------------------------------------------
extern "C" void kernel_launch(void* const* d_in, const int* in_sizes, int n_in,
                              void* d_out, int out_size, void* d_ws, size_t ws_size,
                              hipStream_t stream)
{
    const float* x  = (const float*)d_in[0];
    const float* Wk = (const float*)d_in[1];
    const float* bk = (const float*)d_in[2];
    const float* Wq = (const float*)d_in[3];
    const float* bq = (const float*)d_in[4];
    const float* Wv = (const float*)d_in[5];
    const float* bv = (const float*)d_in[6];
    float* out = (float*)d_out;

    const int M = 2 * TSEQ;               // 8192 rows
    float* Qbuf = (float*)d_ws;
    float* Kbuf = Qbuf + (size_t)M * DMODEL;
    float* Vbuf = Kbuf + (size_t)M * DMODEL;

    dim3 pgrid(M / 64, DMODEL / 64, 3);
    proj_kernel<<<pgrid, dim3(256), 0, stream>>>(x, Wq, bq, Wk, bk, Wv, bv,
                                                 Qbuf, Kbuf, Vbuf);

    dim3 agrid(TSEQ / 64, NHEADS, 2);
    attn_kernel<<<agrid, dim3(256), 0, stream>>>(Qbuf, Kbuf, Vbuf, out);
}

// Round 2
// 676.666 us; speedup vs baseline: 4.0983x; 4.0983x over previous
//
#include <hip/hip_runtime.h>
#include <math.h>

#define TT 4096
#define DM 512
#define NH 8
#define HD 64

typedef float f32x4 __attribute__((ext_vector_type(4)));
typedef short short8 __attribute__((ext_vector_type(8)));

__device__ __forceinline__ unsigned short f2bf(float x) {
    unsigned int u = __builtin_bit_cast(unsigned int, x);
    u = (u + 0x7FFFu + ((u >> 16) & 1u)) >> 16;
    return (unsigned short)u;
}
__device__ __forceinline__ float bf2f(unsigned short h) {
    unsigned int u = ((unsigned int)h) << 16;
    return __builtin_bit_cast(float, u);
}

// ---------------------------------------------------------------------------
// Projection: Y = X @ W^T + bias, then emit split-bf16:
//   z=0: Q  -> (Qhi,Qlo) natural [B*T,512], pre-scaled by 1/sqrt(hd)=0.125
//   z=1: K  -> (Khi,Klo) natural
//   z=2: V  -> (Vthi,Vtlo) transposed per head: [b][h][d=64][T]
// ---------------------------------------------------------------------------
__global__ __launch_bounds__(256) void proj_kernel(
    const float* __restrict__ X,
    const float* __restrict__ Wq, const float* __restrict__ bq,
    const float* __restrict__ Wk, const float* __restrict__ bk,
    const float* __restrict__ Wv, const float* __restrict__ bv,
    unsigned short* __restrict__ Qhi, unsigned short* __restrict__ Qlo,
    unsigned short* __restrict__ Khi, unsigned short* __restrict__ Klo,
    unsigned short* __restrict__ Vthi, unsigned short* __restrict__ Vtlo)
{
    const int z = blockIdx.z;
    const float* __restrict__ W    = (z == 0) ? Wq : (z == 1) ? Wk : Wv;
    const float* __restrict__ bias = (z == 0) ? bq : (z == 1) ? bk : bv;

    const int m0 = blockIdx.x * 64;
    const int n0 = blockIdx.y * 64;
    const int tid = threadIdx.x;
    const int ty = tid >> 4;
    const int tx = tid & 15;

    __shared__ float xs[64][36];
    __shared__ float ws[64][36];
    __shared__ float ts[64][66];

    float acc[4][4] = {};

    for (int k0 = 0; k0 < DM; k0 += 32) {
        #pragma unroll
        for (int rep = 0; rep < 2; ++rep) {
            int idx = rep * 256 + tid;
            int row = idx >> 3;
            int c4  = (idx & 7) * 4;
            *(float4*)&xs[row][c4] = *(const float4*)&X[(size_t)(m0 + row) * DM + k0 + c4];
            *(float4*)&ws[row][c4] = *(const float4*)&W[(size_t)(n0 + row) * DM + k0 + c4];
        }
        __syncthreads();
        #pragma unroll
        for (int kkb = 0; kkb < 8; ++kkb) {
            float4 a[4], bb[4];
            #pragma unroll
            for (int i = 0; i < 4; ++i) a[i]  = *(const float4*)&xs[ty * 4 + i][kkb * 4];
            #pragma unroll
            for (int j = 0; j < 4; ++j) bb[j] = *(const float4*)&ws[tx + 16 * j][kkb * 4];
            #pragma unroll
            for (int i = 0; i < 4; ++i)
                #pragma unroll
                for (int j = 0; j < 4; ++j)
                    acc[i][j] += a[i].x * bb[j].x + a[i].y * bb[j].y
                               + a[i].z * bb[j].z + a[i].w * bb[j].w;
        }
        __syncthreads();
    }

    if (z < 2) {
        unsigned short* __restrict__ Hi = (z == 0) ? Qhi : Khi;
        unsigned short* __restrict__ Lo = (z == 0) ? Qlo : Klo;
        const float sc = (z == 0) ? 0.125f : 1.0f;
        #pragma unroll
        for (int j = 0; j < 4; ++j) {
            int n = n0 + tx + 16 * j;
            float bv_ = bias[n];
            #pragma unroll
            for (int i = 0; i < 4; ++i) {
                int m = m0 + ty * 4 + i;
                float y = (acc[i][j] + bv_) * sc;
                unsigned short hb = f2bf(y);
                unsigned short lb = f2bf(y - bf2f(hb));
                Hi[(size_t)m * DM + n] = hb;
                Lo[(size_t)m * DM + n] = lb;
            }
        }
    } else {
        // transpose through LDS, write [b][h][d][T] hi/lo
        #pragma unroll
        for (int j = 0; j < 4; ++j) {
            int nl = tx + 16 * j;
            float bv_ = bias[n0 + nl];
            #pragma unroll
            for (int i = 0; i < 4; ++i)
                ts[nl][ty * 4 + i] = acc[i][j] + bv_;
        }
        __syncthreads();
        const int dl = tid >> 2;          // 0..63 (d within head)
        const int ch = tid & 3;           // 4 chunks of 16 t's
        const int h_ = n0 >> 6;
        const int bb = m0 >> 12;
        const int t0 = m0 & (TT - 1);
        size_t obase = ((size_t)(bb * NH + h_) * HD + dl) * TT + t0 + ch * 16;
        unsigned int hw[8], lw[8];
        #pragma unroll
        for (int k = 0; k < 8; ++k) {
            float y0 = ts[dl][ch * 16 + 2 * k];
            float y1 = ts[dl][ch * 16 + 2 * k + 1];
            unsigned short h0 = f2bf(y0), h1 = f2bf(y1);
            unsigned short l0 = f2bf(y0 - bf2f(h0)), l1 = f2bf(y1 - bf2f(h1));
            hw[k] = (unsigned int)h0 | ((unsigned int)h1 << 16);
            lw[k] = (unsigned int)l0 | ((unsigned int)l1 << 16);
        }
        uint4 hv0 = {hw[0], hw[1], hw[2], hw[3]};
        uint4 hv1 = {hw[4], hw[5], hw[6], hw[7]};
        uint4 lv0 = {lw[0], lw[1], lw[2], lw[3]};
        uint4 lv1 = {lw[4], lw[5], lw[6], lw[7]};
        *(uint4*)&Vthi[obase]     = hv0;
        *(uint4*)&Vthi[obase + 8] = hv1;
        *(uint4*)&Vtlo[obase]     = lv0;
        *(uint4*)&Vtlo[obase + 8] = lv1;
    }
}

// ---------------------------------------------------------------------------
// Flash attention via split-bf16 MFMA. Reference semantics: S = K @ Q^T
// (K rows = output rows), softmax over q, out = P @ V.
// Block: 256 thr (4 waves), 128 K-rows/block (32 per wave), q-tiles of 64.
// ---------------------------------------------------------------------------
__global__ __launch_bounds__(256, 2) void attn_mfma(
    const unsigned short* __restrict__ Qhi, const unsigned short* __restrict__ Qlo,
    const unsigned short* __restrict__ Khi, const unsigned short* __restrict__ Klo,
    const unsigned short* __restrict__ Vthi, const unsigned short* __restrict__ Vtlo,
    float* __restrict__ Out)
{
    const int b = blockIdx.z, h = blockIdx.y;
    const int r0 = blockIdx.x * 128;
    const int tid = threadIdx.x;
    const int wid = tid >> 6, lane = tid & 63;
    const int lg = lane >> 4, lr = lane & 15;
    const int wr0 = r0 + wid * 32;

    // pitch 72 bf16 = 144 B (16B-aligned rows, uniform bank use on b128)
    __shared__ __attribute__((aligned(16))) unsigned short Qs[128][72]; // Q hi(0-63)/lo(64-127); reused as P-lo
    __shared__ __attribute__((aligned(16))) unsigned short Vs[128][72]; // Vt hi/lo
    __shared__ __attribute__((aligned(16))) unsigned short Ps[128][72]; // P hi

    // K fragments resident in registers: [rowtile][kchunk][hi/lo]
    short8 kf[2][2][2];
    #pragma unroll
    for (int rt = 0; rt < 2; ++rt)
        #pragma unroll
        for (int kc = 0; kc < 2; ++kc) {
            int row = wr0 + rt * 16 + lr;
            size_t g = ((size_t)(b * TT + row)) * DM + h * HD + kc * 32 + lg * 8;
            kf[rt][kc][0] = __builtin_bit_cast(short8, *(const int4*)&Khi[g]);
            kf[rt][kc][1] = __builtin_bit_cast(short8, *(const int4*)&Klo[g]);
        }

    float m_s[2][4], l_s[2][4], alpha[2][4];
    f32x4 oacc[2][4];
    #pragma unroll
    for (int rt = 0; rt < 2; ++rt)
        #pragma unroll
        for (int r = 0; r < 4; ++r) { m_s[rt][r] = -INFINITY; l_s[rt][r] = 0.f; }
    #pragma unroll
    for (int rt = 0; rt < 2; ++rt)
        #pragma unroll
        for (int dt = 0; dt < 4; ++dt) oacc[rt][dt] = (f32x4){0.f, 0.f, 0.f, 0.f};

    for (int c0 = 0; c0 < TT; c0 += 64) {
        __syncthreads();
        // stage Q hi/lo (rows 0..127 of Qs) and Vt hi/lo (rows 0..127 of Vs)
        #pragma unroll
        for (int it = 0; it < 4; ++it) {
            int gi = it * 256 + tid;           // 0..1023
            int fr = gi >> 3, ch = gi & 7;
            const unsigned short* src = (fr < 64) ? Qhi : Qlo;
            size_t g = ((size_t)(b * TT + c0 + (fr & 63))) * DM + h * HD + ch * 8;
            *(int4*)&Qs[fr][ch * 8] = *(const int4*)&src[g];
        }
        #pragma unroll
        for (int it = 0; it < 4; ++it) {
            int gi = it * 256 + tid;
            int fr = gi >> 3, ch = gi & 7;
            const unsigned short* src = (fr < 64) ? Vthi : Vtlo;
            size_t g = ((size_t)((b * NH + h) * HD + (fr & 63))) * TT + c0 + ch * 8;
            *(int4*)&Vs[fr][ch * 8] = *(const int4*)&src[g];
        }
        __syncthreads();

        // S = K @ Q^T : 3-term split (hi*hi + lo*hi + hi*lo)
        f32x4 sacc[2][4];
        #pragma unroll
        for (int rt = 0; rt < 2; ++rt)
            #pragma unroll
            for (int qt = 0; qt < 4; ++qt) sacc[rt][qt] = (f32x4){0.f, 0.f, 0.f, 0.f};
        #pragma unroll
        for (int kc = 0; kc < 2; ++kc) {
            #pragma unroll
            for (int qt = 0; qt < 4; ++qt) {
                short8 qh = __builtin_bit_cast(short8, *(const int4*)&Qs[qt * 16 + lr][kc * 32 + lg * 8]);
                short8 ql = __builtin_bit_cast(short8, *(const int4*)&Qs[64 + qt * 16 + lr][kc * 32 + lg * 8]);
                #pragma unroll
                for (int rt = 0; rt < 2; ++rt) {
                    sacc[rt][qt] = __builtin_amdgcn_mfma_f32_16x16x32_bf16(kf[rt][kc][0], qh, sacc[rt][qt], 0, 0, 0);
                    sacc[rt][qt] = __builtin_amdgcn_mfma_f32_16x16x32_bf16(kf[rt][kc][1], qh, sacc[rt][qt], 0, 0, 0);
                    sacc[rt][qt] = __builtin_amdgcn_mfma_f32_16x16x32_bf16(kf[rt][kc][0], ql, sacc[rt][qt], 0, 0, 0);
                }
            }
        }

        // online softmax over q (rows owned per lane: rt*16 + lg*4 + r)
        #pragma unroll
        for (int rt = 0; rt < 2; ++rt) {
            #pragma unroll
            for (int r = 0; r < 4; ++r) {
                float mx = fmaxf(fmaxf(sacc[rt][0][r], sacc[rt][1][r]),
                                 fmaxf(sacc[rt][2][r], sacc[rt][3][r]));
                mx = fmaxf(mx, __shfl_xor(mx, 1));
                mx = fmaxf(mx, __shfl_xor(mx, 2));
                mx = fmaxf(mx, __shfl_xor(mx, 4));
                mx = fmaxf(mx, __shfl_xor(mx, 8));
                float nm = fmaxf(m_s[rt][r], mx);
                float al = __expf(m_s[rt][r] - nm);
                float sum = 0.f;
                #pragma unroll
                for (int qt = 0; qt < 4; ++qt) {
                    float p = __expf(sacc[rt][qt][r] - nm);
                    sacc[rt][qt][r] = p;
                    sum += p;
                }
                sum += __shfl_xor(sum, 1);
                sum += __shfl_xor(sum, 2);
                sum += __shfl_xor(sum, 4);
                sum += __shfl_xor(sum, 8);
                m_s[rt][r] = nm;
                l_s[rt][r] = l_s[rt][r] * al + sum;
                alpha[rt][r] = al;
            }
        }

        __syncthreads();   // all waves finished reading Qs before P-lo overwrites it

        // write P: hi -> Ps, lo -> Qs (reuse); C-layout row = (l>>4)*4+r
        #pragma unroll
        for (int rt = 0; rt < 2; ++rt)
            #pragma unroll
            for (int qt = 0; qt < 4; ++qt)
                #pragma unroll
                for (int r = 0; r < 4; ++r) {
                    float p = sacc[rt][qt][r];
                    unsigned short ph = f2bf(p);
                    unsigned short pl = f2bf(p - bf2f(ph));
                    int row = wid * 32 + rt * 16 + lg * 4 + r;
                    Ps[row][qt * 16 + lr] = ph;
                    Qs[row][qt * 16 + lr] = pl;
                }

        // rescale output accumulators
        #pragma unroll
        for (int rt = 0; rt < 2; ++rt)
            #pragma unroll
            for (int dt = 0; dt < 4; ++dt)
                #pragma unroll
                for (int r = 0; r < 4; ++r)
                    oacc[rt][dt][r] *= alpha[rt][r];

        // out += P @ V : 3-term split
        #pragma unroll
        for (int qc = 0; qc < 2; ++qc) {
            short8 pf[2], pl_[2];
            #pragma unroll
            for (int rt = 0; rt < 2; ++rt) {
                pf[rt]  = __builtin_bit_cast(short8, *(const int4*)&Ps[wid * 32 + rt * 16 + lr][qc * 32 + lg * 8]);
                pl_[rt] = __builtin_bit_cast(short8, *(const int4*)&Qs[wid * 32 + rt * 16 + lr][qc * 32 + lg * 8]);
            }
            #pragma unroll
            for (int dt = 0; dt < 4; ++dt) {
                short8 vh = __builtin_bit_cast(short8, *(const int4*)&Vs[dt * 16 + lr][qc * 32 + lg * 8]);
                short8 vl = __builtin_bit_cast(short8, *(const int4*)&Vs[64 + dt * 16 + lr][qc * 32 + lg * 8]);
                #pragma unroll
                for (int rt = 0; rt < 2; ++rt) {
                    oacc[rt][dt] = __builtin_amdgcn_mfma_f32_16x16x32_bf16(pf[rt],  vh, oacc[rt][dt], 0, 0, 0);
                    oacc[rt][dt] = __builtin_amdgcn_mfma_f32_16x16x32_bf16(pf[rt],  vl, oacc[rt][dt], 0, 0, 0);
                    oacc[rt][dt] = __builtin_amdgcn_mfma_f32_16x16x32_bf16(pl_[rt], vh, oacc[rt][dt], 0, 0, 0);
                }
            }
        }
    }

    // epilogue: normalize and store
    #pragma unroll
    for (int rt = 0; rt < 2; ++rt)
        #pragma unroll
        for (int dt = 0; dt < 4; ++dt)
            #pragma unroll
            for (int r = 0; r < 4; ++r) {
                int row = wr0 + rt * 16 + lg * 4 + r;
                int d = dt * 16 + lr;
                Out[((size_t)(b * TT + row)) * DM + h * HD + d] = oacc[rt][dt][r] / l_s[rt][r];
            }
}

// ---------------------------------------------------------------------------
extern "C" void kernel_launch(void* const* d_in, const int* in_sizes, int n_in,
                              void* d_out, int out_size, void* d_ws, size_t ws_size,
                              hipStream_t stream)
{
    const float* x  = (const float*)d_in[0];
    const float* Wk = (const float*)d_in[1];
    const float* bk = (const float*)d_in[2];
    const float* Wq = (const float*)d_in[3];
    const float* bq = (const float*)d_in[4];
    const float* Wv = (const float*)d_in[5];
    const float* bv = (const float*)d_in[6];
    float* out = (float*)d_out;

    const size_t SZ = (size_t)2 * TT * DM;   // 4,194,304 elements
    unsigned short* Qhi  = (unsigned short*)d_ws;
    unsigned short* Qlo  = Qhi + SZ;
    unsigned short* Khi  = Qlo + SZ;
    unsigned short* Klo  = Khi + SZ;
    unsigned short* Vthi = Klo + SZ;
    unsigned short* Vtlo = Vthi + SZ;

    dim3 pgrid(2 * TT / 64, DM / 64, 3);
    proj_kernel<<<pgrid, dim3(256), 0, stream>>>(x, Wq, bq, Wk, bk, Wv, bv,
                                                 Qhi, Qlo, Khi, Klo, Vthi, Vtlo);

    dim3 agrid(TT / 128, NH, 2);
    attn_mfma<<<agrid, dim3(256), 0, stream>>>(Qhi, Qlo, Khi, Klo, Vthi, Vtlo, out);
}

// Round 3
// 467.701 us; speedup vs baseline: 5.9294x; 1.4468x over previous
//
#include <hip/hip_runtime.h>
#include <math.h>

#define TT 4096
#define DM 512
#define NH 8
#define HD 64
#define WN (DM * DM)   // 262144 elements per weight matrix

typedef float f32x4 __attribute__((ext_vector_type(4)));
typedef short short8 __attribute__((ext_vector_type(8)));

static __device__ __forceinline__ float bf2f(unsigned short h) {
    unsigned int u = ((unsigned int)h) << 16;
    return __builtin_bit_cast(float, u);
}
// truncation split: hi = trunc_bf16(x), lo = trunc_bf16(x - hi). Net rel err ~2^-15.
static __device__ __forceinline__ void splitbf(float x, unsigned short& hi, unsigned short& lo) {
    unsigned int u = __builtin_bit_cast(unsigned int, x);
    hi = (unsigned short)(u >> 16);
    float r = x - bf2f(hi);
    lo = (unsigned short)(__builtin_bit_cast(unsigned int, r) >> 16);
}

// ---------------------------------------------------------------------------
// Pre-split the three weight matrices into bf16 hi/lo. grid (128, 3), 256 thr.
// ---------------------------------------------------------------------------
__global__ __launch_bounds__(256) void wsplit(
    const float* __restrict__ Wq, const float* __restrict__ Wk, const float* __restrict__ Wv,
    unsigned short* __restrict__ Whi, unsigned short* __restrict__ Wlo)
{
    const int z = blockIdx.y;
    const float* __restrict__ src = (z == 0) ? Wq : (z == 1) ? Wk : Wv;
    const int i = (blockIdx.x * 256 + threadIdx.x) * 8;
    float4 a = *(const float4*)&src[i];
    float4 b = *(const float4*)&src[i + 4];
    float v[8] = {a.x, a.y, a.z, a.w, b.x, b.y, b.z, b.w};
    unsigned short hb[8], lb[8];
    #pragma unroll
    for (int k = 0; k < 8; ++k) splitbf(v[k], hb[k], lb[k]);
    uint4 hv, lv;
    hv.x = (unsigned int)hb[0] | ((unsigned int)hb[1] << 16);
    hv.y = (unsigned int)hb[2] | ((unsigned int)hb[3] << 16);
    hv.z = (unsigned int)hb[4] | ((unsigned int)hb[5] << 16);
    hv.w = (unsigned int)hb[6] | ((unsigned int)hb[7] << 16);
    lv.x = (unsigned int)lb[0] | ((unsigned int)lb[1] << 16);
    lv.y = (unsigned int)lb[2] | ((unsigned int)lb[3] << 16);
    lv.z = (unsigned int)lb[4] | ((unsigned int)lb[5] << 16);
    lv.w = (unsigned int)lb[6] | ((unsigned int)lb[7] << 16);
    *(uint4*)&Whi[(size_t)z * WN + i] = hv;
    *(uint4*)&Wlo[(size_t)z * WN + i] = lv;
}

// ---------------------------------------------------------------------------
// Projection via 3-term split-bf16 MFMA. Y = X @ W^T + bias.
// grid (M/128, 512/64, 3), 256 thr (4 waves), BM=128 BN=64 BK=64.
//   z=0: Q -> (Qhi,Qlo) [m][n], pre-scaled 0.125
//   z=1: K -> (Khi,Klo) [m][n]
//   z=2: V -> (Vthi,Vtlo) transposed [b][h][d][T]
// ---------------------------------------------------------------------------
__global__ __launch_bounds__(256, 2) void proj_mfma(
    const float* __restrict__ X,
    const unsigned short* __restrict__ Whi, const unsigned short* __restrict__ Wlo,
    const float* __restrict__ bq, const float* __restrict__ bk, const float* __restrict__ bv,
    unsigned short* __restrict__ Qhi, unsigned short* __restrict__ Qlo,
    unsigned short* __restrict__ Khi, unsigned short* __restrict__ Klo,
    unsigned short* __restrict__ Vthi, unsigned short* __restrict__ Vtlo)
{
    const int z = blockIdx.z;
    const int m0 = blockIdx.x * 128;
    const int n0 = blockIdx.y * 64;
    const int tid = threadIdx.x;
    const int wid = tid >> 6, lane = tid & 63;
    const int lg = lane >> 4, lr = lane & 15;

    __shared__ __attribute__((aligned(16))) unsigned short smem[384 * 72];
    auto Xh  = (unsigned short(*)[72])(smem);
    auto Xl  = (unsigned short(*)[72])(smem + 128 * 72);
    auto Wh2 = (unsigned short(*)[72])(smem + 256 * 72);
    auto Wl2 = (unsigned short(*)[72])(smem + 320 * 72);

    const unsigned short* __restrict__ Wh = Whi + (size_t)z * WN;
    const unsigned short* __restrict__ Wl = Wlo + (size_t)z * WN;

    f32x4 acc[2][4];
    #pragma unroll
    for (int rt = 0; rt < 2; ++rt)
        #pragma unroll
        for (int nt = 0; nt < 4; ++nt) acc[rt][nt] = (f32x4){0.f, 0.f, 0.f, 0.f};

    const int xr = tid >> 1;            // 0..127
    const int xc = (tid & 1) * 32;      // 0 or 32

    for (int k0 = 0; k0 < DM; k0 += 64) {
        // --- stage X (fp32 -> split bf16 on the fly), 32 elems/thread ---
        #pragma unroll
        for (int w = 0; w < 4; ++w) {
            float4 fa = *(const float4*)&X[(size_t)(m0 + xr) * DM + k0 + xc + w * 8];
            float4 fb = *(const float4*)&X[(size_t)(m0 + xr) * DM + k0 + xc + w * 8 + 4];
            float v[8] = {fa.x, fa.y, fa.z, fa.w, fb.x, fb.y, fb.z, fb.w};
            unsigned short hb[8], lb[8];
            #pragma unroll
            for (int k = 0; k < 8; ++k) splitbf(v[k], hb[k], lb[k]);
            uint4 hv, lv;
            hv.x = (unsigned int)hb[0] | ((unsigned int)hb[1] << 16);
            hv.y = (unsigned int)hb[2] | ((unsigned int)hb[3] << 16);
            hv.z = (unsigned int)hb[4] | ((unsigned int)hb[5] << 16);
            hv.w = (unsigned int)hb[6] | ((unsigned int)hb[7] << 16);
            lv.x = (unsigned int)lb[0] | ((unsigned int)lb[1] << 16);
            lv.y = (unsigned int)lb[2] | ((unsigned int)lb[3] << 16);
            lv.z = (unsigned int)lb[4] | ((unsigned int)lb[5] << 16);
            lv.w = (unsigned int)lb[6] | ((unsigned int)lb[7] << 16);
            *(uint4*)&Xh[xr][xc + w * 8] = hv;
            *(uint4*)&Xl[xr][xc + w * 8] = lv;
        }
        // --- stage W (copy pre-split bf16) ---
        #pragma unroll
        for (int it = 0; it < 2; ++it) {
            int i2 = it * 256 + tid;     // 0..511
            int fr = i2 >> 3, ch = i2 & 7;
            *(int4*)&Wh2[fr][ch * 8] = *(const int4*)&Wh[(size_t)(n0 + fr) * DM + k0 + ch * 8];
            *(int4*)&Wl2[fr][ch * 8] = *(const int4*)&Wl[(size_t)(n0 + fr) * DM + k0 + ch * 8];
        }
        __syncthreads();

        __builtin_amdgcn_s_setprio(1);
        #pragma unroll
        for (int kc = 0; kc < 2; ++kc) {
            short8 xa[2][2];
            #pragma unroll
            for (int rt = 0; rt < 2; ++rt) {
                xa[rt][0] = __builtin_bit_cast(short8, *(const int4*)&Xh[wid * 32 + rt * 16 + lr][kc * 32 + lg * 8]);
                xa[rt][1] = __builtin_bit_cast(short8, *(const int4*)&Xl[wid * 32 + rt * 16 + lr][kc * 32 + lg * 8]);
            }
            #pragma unroll
            for (int nt = 0; nt < 4; ++nt) {
                short8 wh = __builtin_bit_cast(short8, *(const int4*)&Wh2[nt * 16 + lr][kc * 32 + lg * 8]);
                short8 wl = __builtin_bit_cast(short8, *(const int4*)&Wl2[nt * 16 + lr][kc * 32 + lg * 8]);
                #pragma unroll
                for (int rt = 0; rt < 2; ++rt) {
                    acc[rt][nt] = __builtin_amdgcn_mfma_f32_16x16x32_bf16(xa[rt][0], wh, acc[rt][nt], 0, 0, 0);
                    acc[rt][nt] = __builtin_amdgcn_mfma_f32_16x16x32_bf16(xa[rt][1], wh, acc[rt][nt], 0, 0, 0);
                    acc[rt][nt] = __builtin_amdgcn_mfma_f32_16x16x32_bf16(xa[rt][0], wl, acc[rt][nt], 0, 0, 0);
                }
            }
        }
        __builtin_amdgcn_s_setprio(0);
        __syncthreads();
    }

    if (z < 2) {
        const float* __restrict__ bias = (z == 0) ? bq : bk;
        unsigned short* __restrict__ Hi = (z == 0) ? Qhi : Khi;
        unsigned short* __restrict__ Lo = (z == 0) ? Qlo : Klo;
        const float sc = (z == 0) ? 0.125f : 1.0f;
        #pragma unroll
        for (int nt = 0; nt < 4; ++nt) {
            int n = n0 + nt * 16 + lr;
            float bv_ = bias[n];
            #pragma unroll
            for (int rt = 0; rt < 2; ++rt)
                #pragma unroll
                for (int r = 0; r < 4; ++r) {
                    int m = m0 + wid * 32 + rt * 16 + lg * 4 + r;
                    float y = (acc[rt][nt][r] + bv_) * sc;
                    unsigned short hb, lb;
                    splitbf(y, hb, lb);
                    Hi[(size_t)m * DM + n] = hb;
                    Lo[(size_t)m * DM + n] = lb;
                }
        }
    } else {
        // V: pack hi|lo into u32, bounce through LDS, write transposed [b][h][d][T]
        unsigned int* Tk = (unsigned int*)smem;   // [64][132] u32, 33.8 KB (aliases X tiles)
        #pragma unroll
        for (int nt = 0; nt < 4; ++nt) {
            int d = nt * 16 + lr;
            float bv_ = bv[n0 + d];
            #pragma unroll
            for (int rt = 0; rt < 2; ++rt)
                #pragma unroll
                for (int r = 0; r < 4; ++r) {
                    int t = wid * 32 + rt * 16 + lg * 4 + r;
                    float y = acc[rt][nt][r] + bv_;
                    unsigned short hb, lb;
                    splitbf(y, hb, lb);
                    Tk[d * 132 + t] = (unsigned int)hb | ((unsigned int)lb << 16);
                }
        }
        __syncthreads();
        const int dl = tid >> 2, tq = tid & 3;
        const int bb = m0 >> 12, t0 = m0 & (TT - 1), h = n0 >> 6;
        size_t obase = ((size_t)((bb * NH + h) * HD + dl)) * TT + t0 + tq * 32;
        unsigned int hw[16], lw[16];
        #pragma unroll
        for (int k = 0; k < 16; ++k) {
            unsigned int u0 = Tk[dl * 132 + tq * 32 + 2 * k];
            unsigned int u1 = Tk[dl * 132 + tq * 32 + 2 * k + 1];
            hw[k] = (u0 & 0xFFFFu) | (u1 << 16);
            lw[k] = (u0 >> 16) | (u1 & 0xFFFF0000u);
        }
        #pragma unroll
        for (int j = 0; j < 4; ++j) {
            uint4 hv = {hw[4 * j], hw[4 * j + 1], hw[4 * j + 2], hw[4 * j + 3]};
            uint4 lv = {lw[4 * j], lw[4 * j + 1], lw[4 * j + 2], lw[4 * j + 3]};
            *(uint4*)&Vthi[obase + j * 8] = hv;
            *(uint4*)&Vtlo[obase + j * 8] = lv;
        }
    }
}

// ---------------------------------------------------------------------------
// Flash attention via split-bf16 MFMA. S = K @ Q^T, softmax over q, out = P@V.
// 4 waves, 128 K-rows/block, q-tiles of 64. Register-prefetched Q/V staging,
// 2 barriers/step, dedicated P-lo buffer (no pre-P-write barrier).
// ---------------------------------------------------------------------------
__global__ __launch_bounds__(256, 2) void attn_mfma(
    const unsigned short* __restrict__ Qhi, const unsigned short* __restrict__ Qlo,
    const unsigned short* __restrict__ Khi, const unsigned short* __restrict__ Klo,
    const unsigned short* __restrict__ Vthi, const unsigned short* __restrict__ Vtlo,
    float* __restrict__ Out)
{
    const int b = blockIdx.z, h = blockIdx.y;
    const int r0 = blockIdx.x * 128;
    const int tid = threadIdx.x;
    const int wid = tid >> 6, lane = tid & 63;
    const int lg = lane >> 4, lr = lane & 15;
    const int wr0 = r0 + wid * 32;

    __shared__ __attribute__((aligned(16))) unsigned short Qs[128][72];
    __shared__ __attribute__((aligned(16))) unsigned short Vs[128][72];
    __shared__ __attribute__((aligned(16))) unsigned short Ps[128][72];
    __shared__ __attribute__((aligned(16))) unsigned short Pl[128][72];

    // K fragments resident in registers
    short8 kf[2][2][2];
    #pragma unroll
    for (int rt = 0; rt < 2; ++rt)
        #pragma unroll
        for (int kc = 0; kc < 2; ++kc) {
            int row = wr0 + rt * 16 + lr;
            size_t g = ((size_t)(b * TT + row)) * DM + h * HD + kc * 32 + lg * 8;
            kf[rt][kc][0] = __builtin_bit_cast(short8, *(const int4*)&Khi[g]);
            kf[rt][kc][1] = __builtin_bit_cast(short8, *(const int4*)&Klo[g]);
        }

    // prologue: prefetch tile 0 into registers
    int4 qreg[4], vreg[4];
    #pragma unroll
    for (int it = 0; it < 4; ++it) {
        int gi = it * 256 + tid, fr = gi >> 3, ch = gi & 7;
        const unsigned short* qsrc = (fr < 64) ? Qhi : Qlo;
        qreg[it] = *(const int4*)&qsrc[((size_t)(b * TT + (fr & 63))) * DM + h * HD + ch * 8];
        const unsigned short* vsrc = (fr < 64) ? Vthi : Vtlo;
        vreg[it] = *(const int4*)&vsrc[((size_t)((b * NH + h) * HD + (fr & 63))) * TT + ch * 8];
    }

    float m_s[2][4], l_s[2][4], alpha[2][4];
    f32x4 oacc[2][4];
    #pragma unroll
    for (int rt = 0; rt < 2; ++rt)
        #pragma unroll
        for (int r = 0; r < 4; ++r) { m_s[rt][r] = -INFINITY; l_s[rt][r] = 0.f; }
    #pragma unroll
    for (int rt = 0; rt < 2; ++rt)
        #pragma unroll
        for (int dt = 0; dt < 4; ++dt) oacc[rt][dt] = (f32x4){0.f, 0.f, 0.f, 0.f};

    for (int c0 = 0; c0 < TT; c0 += 64) {
        // write staged tile from registers
        #pragma unroll
        for (int it = 0; it < 4; ++it) {
            int gi = it * 256 + tid, fr = gi >> 3, ch = gi & 7;
            *(int4*)&Qs[fr][ch * 8] = qreg[it];
            *(int4*)&Vs[fr][ch * 8] = vreg[it];
        }
        __syncthreads();

        // issue prefetch for next tile (overlaps whole step's compute)
        int cn = c0 + 64; if (cn >= TT) cn = 0;
        #pragma unroll
        for (int it = 0; it < 4; ++it) {
            int gi = it * 256 + tid, fr = gi >> 3, ch = gi & 7;
            const unsigned short* qsrc = (fr < 64) ? Qhi : Qlo;
            qreg[it] = *(const int4*)&qsrc[((size_t)(b * TT + cn + (fr & 63))) * DM + h * HD + ch * 8];
            const unsigned short* vsrc = (fr < 64) ? Vthi : Vtlo;
            vreg[it] = *(const int4*)&vsrc[((size_t)((b * NH + h) * HD + (fr & 63))) * TT + cn + ch * 8];
        }

        // S = K @ Q^T : 3-term split
        f32x4 sacc[2][4];
        #pragma unroll
        for (int rt = 0; rt < 2; ++rt)
            #pragma unroll
            for (int qt = 0; qt < 4; ++qt) sacc[rt][qt] = (f32x4){0.f, 0.f, 0.f, 0.f};
        __builtin_amdgcn_s_setprio(1);
        #pragma unroll
        for (int kc = 0; kc < 2; ++kc) {
            #pragma unroll
            for (int qt = 0; qt < 4; ++qt) {
                short8 qh = __builtin_bit_cast(short8, *(const int4*)&Qs[qt * 16 + lr][kc * 32 + lg * 8]);
                short8 ql = __builtin_bit_cast(short8, *(const int4*)&Qs[64 + qt * 16 + lr][kc * 32 + lg * 8]);
                #pragma unroll
                for (int rt = 0; rt < 2; ++rt) {
                    sacc[rt][qt] = __builtin_amdgcn_mfma_f32_16x16x32_bf16(kf[rt][kc][0], qh, sacc[rt][qt], 0, 0, 0);
                    sacc[rt][qt] = __builtin_amdgcn_mfma_f32_16x16x32_bf16(kf[rt][kc][1], qh, sacc[rt][qt], 0, 0, 0);
                    sacc[rt][qt] = __builtin_amdgcn_mfma_f32_16x16x32_bf16(kf[rt][kc][0], ql, sacc[rt][qt], 0, 0, 0);
                }
            }
        }
        __builtin_amdgcn_s_setprio(0);

        // online softmax over q
        #pragma unroll
        for (int rt = 0; rt < 2; ++rt) {
            #pragma unroll
            for (int r = 0; r < 4; ++r) {
                float mx = fmaxf(fmaxf(sacc[rt][0][r], sacc[rt][1][r]),
                                 fmaxf(sacc[rt][2][r], sacc[rt][3][r]));
                mx = fmaxf(mx, __shfl_xor(mx, 1));
                mx = fmaxf(mx, __shfl_xor(mx, 2));
                mx = fmaxf(mx, __shfl_xor(mx, 4));
                mx = fmaxf(mx, __shfl_xor(mx, 8));
                float nm = fmaxf(m_s[rt][r], mx);
                float al = __expf(m_s[rt][r] - nm);
                float sum = 0.f;
                #pragma unroll
                for (int qt = 0; qt < 4; ++qt) {
                    float p = __expf(sacc[rt][qt][r] - nm);
                    sacc[rt][qt][r] = p;
                    sum += p;
                }
                sum += __shfl_xor(sum, 1);
                sum += __shfl_xor(sum, 2);
                sum += __shfl_xor(sum, 4);
                sum += __shfl_xor(sum, 8);
                m_s[rt][r] = nm;
                l_s[rt][r] = l_s[rt][r] * al + sum;
                alpha[rt][r] = al;
            }
        }

        // write P hi/lo (own wave's rows only — no barrier needed)
        #pragma unroll
        for (int rt = 0; rt < 2; ++rt)
            #pragma unroll
            for (int qt = 0; qt < 4; ++qt)
                #pragma unroll
                for (int r = 0; r < 4; ++r) {
                    float p = sacc[rt][qt][r];
                    unsigned short ph, pll;
                    splitbf(p, ph, pll);
                    int row = wid * 32 + rt * 16 + lg * 4 + r;
                    Ps[row][qt * 16 + lr] = ph;
                    Pl[row][qt * 16 + lr] = pll;
                }

        // rescale output accumulators
        #pragma unroll
        for (int rt = 0; rt < 2; ++rt)
            #pragma unroll
            for (int dt = 0; dt < 4; ++dt)
                #pragma unroll
                for (int r = 0; r < 4; ++r)
                    oacc[rt][dt][r] *= alpha[rt][r];

        // out += P @ V : 3-term split
        __builtin_amdgcn_s_setprio(1);
        #pragma unroll
        for (int qc = 0; qc < 2; ++qc) {
            short8 pf[2], pl_[2];
            #pragma unroll
            for (int rt = 0; rt < 2; ++rt) {
                pf[rt]  = __builtin_bit_cast(short8, *(const int4*)&Ps[wid * 32 + rt * 16 + lr][qc * 32 + lg * 8]);
                pl_[rt] = __builtin_bit_cast(short8, *(const int4*)&Pl[wid * 32 + rt * 16 + lr][qc * 32 + lg * 8]);
            }
            #pragma unroll
            for (int dt = 0; dt < 4; ++dt) {
                short8 vh = __builtin_bit_cast(short8, *(const int4*)&Vs[dt * 16 + lr][qc * 32 + lg * 8]);
                short8 vl = __builtin_bit_cast(short8, *(const int4*)&Vs[64 + dt * 16 + lr][qc * 32 + lg * 8]);
                #pragma unroll
                for (int rt = 0; rt < 2; ++rt) {
                    oacc[rt][dt] = __builtin_amdgcn_mfma_f32_16x16x32_bf16(pf[rt],  vh, oacc[rt][dt], 0, 0, 0);
                    oacc[rt][dt] = __builtin_amdgcn_mfma_f32_16x16x32_bf16(pf[rt],  vl, oacc[rt][dt], 0, 0, 0);
                    oacc[rt][dt] = __builtin_amdgcn_mfma_f32_16x16x32_bf16(pl_[rt], vh, oacc[rt][dt], 0, 0, 0);
                }
            }
        }
        __builtin_amdgcn_s_setprio(0);
        __syncthreads();   // all waves done reading Qs/Vs before next tile's writes
    }

    // epilogue: normalize and store
    #pragma unroll
    for (int rt = 0; rt < 2; ++rt)
        #pragma unroll
        for (int dt = 0; dt < 4; ++dt)
            #pragma unroll
            for (int r = 0; r < 4; ++r) {
                int row = wr0 + rt * 16 + lg * 4 + r;
                int d = dt * 16 + lr;
                Out[((size_t)(b * TT + row)) * DM + h * HD + d] = oacc[rt][dt][r] / l_s[rt][r];
            }
}

// ---------------------------------------------------------------------------
extern "C" void kernel_launch(void* const* d_in, const int* in_sizes, int n_in,
                              void* d_out, int out_size, void* d_ws, size_t ws_size,
                              hipStream_t stream)
{
    const float* x  = (const float*)d_in[0];
    const float* Wk = (const float*)d_in[1];
    const float* bk = (const float*)d_in[2];
    const float* Wq = (const float*)d_in[3];
    const float* bq = (const float*)d_in[4];
    const float* Wv = (const float*)d_in[5];
    const float* bv = (const float*)d_in[6];
    float* out = (float*)d_out;

    const size_t SZ = (size_t)2 * TT * DM;   // 4,194,304 elements
    unsigned short* Qhi  = (unsigned short*)d_ws;
    unsigned short* Qlo  = Qhi + SZ;
    unsigned short* Khi  = Qlo + SZ;
    unsigned short* Klo  = Khi + SZ;
    unsigned short* Vthi = Klo + SZ;
    unsigned short* Vtlo = Vthi + SZ;
    unsigned short* Whi  = Vtlo + SZ;        // 3*WN
    unsigned short* Wlo  = Whi + (size_t)3 * WN;

    wsplit<<<dim3(WN / 2048, 3), dim3(256), 0, stream>>>(Wq, Wk, Wv, Whi, Wlo);

    dim3 pgrid(2 * TT / 128, DM / 64, 3);
    proj_mfma<<<pgrid, dim3(256), 0, stream>>>(x, Whi, Wlo, bq, bk, bv,
                                               Qhi, Qlo, Khi, Klo, Vthi, Vtlo);

    dim3 agrid(TT / 128, NH, 2);
    attn_mfma<<<agrid, dim3(256), 0, stream>>>(Qhi, Qlo, Khi, Klo, Vthi, Vtlo, out);
}

// Round 4
// 464.138 us; speedup vs baseline: 5.9749x; 1.0077x over previous
//
#include <hip/hip_runtime.h>
#include <math.h>

#define TT 4096
#define DM 512
#define NH 8
#define HD 64
#define WN (DM * DM)   // 262144 elements per weight matrix

typedef float f32x4 __attribute__((ext_vector_type(4)));
typedef short short8 __attribute__((ext_vector_type(8)));

static __device__ __forceinline__ float bf2f(unsigned short h) {
    unsigned int u = ((unsigned int)h) << 16;
    return __builtin_bit_cast(float, u);
}
// truncation split: hi = trunc_bf16(x), lo = trunc_bf16(x - hi). Net rel err ~2^-15.
static __device__ __forceinline__ void splitbf(float x, unsigned short& hi, unsigned short& lo) {
    unsigned int u = __builtin_bit_cast(unsigned int, x);
    hi = (unsigned short)(u >> 16);
    float r = x - bf2f(hi);
    lo = (unsigned short)(__builtin_bit_cast(unsigned int, r) >> 16);
}
// Q-row permutation: LDS row rho holds global q-row qperm(rho). Maps MFMA C-rows
// (lg*4+r) onto PV B-frag k-slots (lg*8+j) so P stays in registers.
static __device__ __forceinline__ int qperm(int r) {
    return ((r >> 5) << 5) | (((r >> 2) & 3) << 3) | (((r >> 4) & 1) << 2) | (r & 3);
}

// ---------------------------------------------------------------------------
// Pre-split the three weight matrices into bf16 hi/lo. grid (128, 3), 256 thr.
// ---------------------------------------------------------------------------
__global__ __launch_bounds__(256) void wsplit(
    const float* __restrict__ Wq, const float* __restrict__ Wk, const float* __restrict__ Wv,
    unsigned short* __restrict__ Whi, unsigned short* __restrict__ Wlo)
{
    const int z = blockIdx.y;
    const float* __restrict__ src = (z == 0) ? Wq : (z == 1) ? Wk : Wv;
    const int i = (blockIdx.x * 256 + threadIdx.x) * 8;
    float4 a = *(const float4*)&src[i];
    float4 b = *(const float4*)&src[i + 4];
    float v[8] = {a.x, a.y, a.z, a.w, b.x, b.y, b.z, b.w};
    unsigned short hb[8], lb[8];
    #pragma unroll
    for (int k = 0; k < 8; ++k) splitbf(v[k], hb[k], lb[k]);
    uint4 hv, lv;
    hv.x = (unsigned int)hb[0] | ((unsigned int)hb[1] << 16);
    hv.y = (unsigned int)hb[2] | ((unsigned int)hb[3] << 16);
    hv.z = (unsigned int)hb[4] | ((unsigned int)hb[5] << 16);
    hv.w = (unsigned int)hb[6] | ((unsigned int)hb[7] << 16);
    lv.x = (unsigned int)lb[0] | ((unsigned int)lb[1] << 16);
    lv.y = (unsigned int)lb[2] | ((unsigned int)lb[3] << 16);
    lv.z = (unsigned int)lb[4] | ((unsigned int)lb[5] << 16);
    lv.w = (unsigned int)lb[6] | ((unsigned int)lb[7] << 16);
    *(uint4*)&Whi[(size_t)z * WN + i] = hv;
    *(uint4*)&Wlo[(size_t)z * WN + i] = lv;
}

// ---------------------------------------------------------------------------
// Projection via 3-term split-bf16 MFMA. Y = X @ W^T + bias.
// grid (M/128, 512/64, 3), 256 thr (4 waves), BM=128 BN=64 BK=64.
// ---------------------------------------------------------------------------
__global__ __launch_bounds__(256, 2) void proj_mfma(
    const float* __restrict__ X,
    const unsigned short* __restrict__ Whi, const unsigned short* __restrict__ Wlo,
    const float* __restrict__ bq, const float* __restrict__ bk, const float* __restrict__ bv,
    unsigned short* __restrict__ Qhi, unsigned short* __restrict__ Qlo,
    unsigned short* __restrict__ Khi, unsigned short* __restrict__ Klo,
    unsigned short* __restrict__ Vthi, unsigned short* __restrict__ Vtlo)
{
    const int z = blockIdx.z;
    const int m0 = blockIdx.x * 128;
    const int n0 = blockIdx.y * 64;
    const int tid = threadIdx.x;
    const int wid = tid >> 6, lane = tid & 63;
    const int lg = lane >> 4, lr = lane & 15;

    __shared__ __attribute__((aligned(16))) unsigned short smem[384 * 72];
    auto Xh  = (unsigned short(*)[72])(smem);
    auto Xl  = (unsigned short(*)[72])(smem + 128 * 72);
    auto Wh2 = (unsigned short(*)[72])(smem + 256 * 72);
    auto Wl2 = (unsigned short(*)[72])(smem + 320 * 72);

    const unsigned short* __restrict__ Wh = Whi + (size_t)z * WN;
    const unsigned short* __restrict__ Wl = Wlo + (size_t)z * WN;

    f32x4 acc[2][4];
    #pragma unroll
    for (int rt = 0; rt < 2; ++rt)
        #pragma unroll
        for (int nt = 0; nt < 4; ++nt) acc[rt][nt] = (f32x4){0.f, 0.f, 0.f, 0.f};

    const int xr = tid >> 1;
    const int xc = (tid & 1) * 32;

    for (int k0 = 0; k0 < DM; k0 += 64) {
        #pragma unroll
        for (int w = 0; w < 4; ++w) {
            float4 fa = *(const float4*)&X[(size_t)(m0 + xr) * DM + k0 + xc + w * 8];
            float4 fb = *(const float4*)&X[(size_t)(m0 + xr) * DM + k0 + xc + w * 8 + 4];
            float v[8] = {fa.x, fa.y, fa.z, fa.w, fb.x, fb.y, fb.z, fb.w};
            unsigned short hb[8], lb[8];
            #pragma unroll
            for (int k = 0; k < 8; ++k) splitbf(v[k], hb[k], lb[k]);
            uint4 hv, lv;
            hv.x = (unsigned int)hb[0] | ((unsigned int)hb[1] << 16);
            hv.y = (unsigned int)hb[2] | ((unsigned int)hb[3] << 16);
            hv.z = (unsigned int)hb[4] | ((unsigned int)hb[5] << 16);
            hv.w = (unsigned int)hb[6] | ((unsigned int)hb[7] << 16);
            lv.x = (unsigned int)lb[0] | ((unsigned int)lb[1] << 16);
            lv.y = (unsigned int)lb[2] | ((unsigned int)lb[3] << 16);
            lv.z = (unsigned int)lb[4] | ((unsigned int)lb[5] << 16);
            lv.w = (unsigned int)lb[6] | ((unsigned int)lb[7] << 16);
            *(uint4*)&Xh[xr][xc + w * 8] = hv;
            *(uint4*)&Xl[xr][xc + w * 8] = lv;
        }
        #pragma unroll
        for (int it = 0; it < 2; ++it) {
            int i2 = it * 256 + tid;
            int fr = i2 >> 3, ch = i2 & 7;
            *(int4*)&Wh2[fr][ch * 8] = *(const int4*)&Wh[(size_t)(n0 + fr) * DM + k0 + ch * 8];
            *(int4*)&Wl2[fr][ch * 8] = *(const int4*)&Wl[(size_t)(n0 + fr) * DM + k0 + ch * 8];
        }
        __syncthreads();

        __builtin_amdgcn_s_setprio(1);
        #pragma unroll
        for (int kc = 0; kc < 2; ++kc) {
            short8 xa[2][2];
            #pragma unroll
            for (int rt = 0; rt < 2; ++rt) {
                xa[rt][0] = __builtin_bit_cast(short8, *(const int4*)&Xh[wid * 32 + rt * 16 + lr][kc * 32 + lg * 8]);
                xa[rt][1] = __builtin_bit_cast(short8, *(const int4*)&Xl[wid * 32 + rt * 16 + lr][kc * 32 + lg * 8]);
            }
            #pragma unroll
            for (int nt = 0; nt < 4; ++nt) {
                short8 wh = __builtin_bit_cast(short8, *(const int4*)&Wh2[nt * 16 + lr][kc * 32 + lg * 8]);
                short8 wl = __builtin_bit_cast(short8, *(const int4*)&Wl2[nt * 16 + lr][kc * 32 + lg * 8]);
                #pragma unroll
                for (int rt = 0; rt < 2; ++rt) {
                    acc[rt][nt] = __builtin_amdgcn_mfma_f32_16x16x32_bf16(xa[rt][0], wh, acc[rt][nt], 0, 0, 0);
                    acc[rt][nt] = __builtin_amdgcn_mfma_f32_16x16x32_bf16(xa[rt][1], wh, acc[rt][nt], 0, 0, 0);
                    acc[rt][nt] = __builtin_amdgcn_mfma_f32_16x16x32_bf16(xa[rt][0], wl, acc[rt][nt], 0, 0, 0);
                }
            }
        }
        __builtin_amdgcn_s_setprio(0);
        __syncthreads();
    }

    if (z < 2) {
        const float* __restrict__ bias = (z == 0) ? bq : bk;
        unsigned short* __restrict__ Hi = (z == 0) ? Qhi : Khi;
        unsigned short* __restrict__ Lo = (z == 0) ? Qlo : Klo;
        const float sc = (z == 0) ? 0.125f : 1.0f;
        #pragma unroll
        for (int nt = 0; nt < 4; ++nt) {
            int n = n0 + nt * 16 + lr;
            float bv_ = bias[n];
            #pragma unroll
            for (int rt = 0; rt < 2; ++rt)
                #pragma unroll
                for (int r = 0; r < 4; ++r) {
                    int m = m0 + wid * 32 + rt * 16 + lg * 4 + r;
                    float y = (acc[rt][nt][r] + bv_) * sc;
                    unsigned short hb, lb;
                    splitbf(y, hb, lb);
                    Hi[(size_t)m * DM + n] = hb;
                    Lo[(size_t)m * DM + n] = lb;
                }
        }
    } else {
        unsigned int* Tk = (unsigned int*)smem;
        #pragma unroll
        for (int nt = 0; nt < 4; ++nt) {
            int d = nt * 16 + lr;
            float bv_ = bv[n0 + d];
            #pragma unroll
            for (int rt = 0; rt < 2; ++rt)
                #pragma unroll
                for (int r = 0; r < 4; ++r) {
                    int t = wid * 32 + rt * 16 + lg * 4 + r;
                    float y = acc[rt][nt][r] + bv_;
                    unsigned short hb, lb;
                    splitbf(y, hb, lb);
                    Tk[d * 132 + t] = (unsigned int)hb | ((unsigned int)lb << 16);
                }
        }
        __syncthreads();
        const int dl = tid >> 2, tq = tid & 3;
        const int bb = m0 >> 12, t0 = m0 & (TT - 1), h = n0 >> 6;
        size_t obase = ((size_t)((bb * NH + h) * HD + dl)) * TT + t0 + tq * 32;
        unsigned int hw[16], lw[16];
        #pragma unroll
        for (int k = 0; k < 16; ++k) {
            unsigned int u0 = Tk[dl * 132 + tq * 32 + 2 * k];
            unsigned int u1 = Tk[dl * 132 + tq * 32 + 2 * k + 1];
            hw[k] = (u0 & 0xFFFFu) | (u1 << 16);
            lw[k] = (u0 >> 16) | (u1 & 0xFFFF0000u);
        }
        #pragma unroll
        for (int j = 0; j < 4; ++j) {
            uint4 hv = {hw[4 * j], hw[4 * j + 1], hw[4 * j + 2], hw[4 * j + 3]};
            uint4 lv = {lw[4 * j], lw[4 * j + 1], lw[4 * j + 2], lw[4 * j + 3]};
            *(uint4*)&Vthi[obase + j * 8] = hv;
            *(uint4*)&Vtlo[obase + j * 8] = lv;
        }
    }
}

// ---------------------------------------------------------------------------
// Flash attention, operand-swapped: S^T = mfma(Q,K) (row=q~, col=krow),
// out^T = mfma(V^T,P) (row=d, col=krow). Q rows staged under qperm so the
// P fragments are lane-local register packs (no P LDS, no cross-lane P moves).
// grid (T/128, NH, 2), 256 thr (4 waves), 32 krows/wave, q-tiles of 64.
// ---------------------------------------------------------------------------
__global__ __launch_bounds__(256, 3) void attn_mfma(
    const unsigned short* __restrict__ Qhi, const unsigned short* __restrict__ Qlo,
    const unsigned short* __restrict__ Khi, const unsigned short* __restrict__ Klo,
    const unsigned short* __restrict__ Vthi, const unsigned short* __restrict__ Vtlo,
    float* __restrict__ Out)
{
    const int b = blockIdx.z, h = blockIdx.y;
    const int r0 = blockIdx.x * 128;
    const int tid = threadIdx.x;
    const int wid = tid >> 6, lane = tid & 63;
    const int lg = lane >> 4, lr = lane & 15;
    const int wr0 = r0 + wid * 32;

    __shared__ __attribute__((aligned(16))) unsigned short Qs[128][72]; // permuted q rows: hi 0-63, lo 64-127
    __shared__ __attribute__((aligned(16))) unsigned short Vs[128][72]; // V^T rows d: hi 0-63, lo 64-127

    // K fragments (B-operand: col=krow=lr, k=d) resident in registers
    short8 kf[2][2][2];
    #pragma unroll
    for (int rt = 0; rt < 2; ++rt)
        #pragma unroll
        for (int kc = 0; kc < 2; ++kc) {
            int row = wr0 + rt * 16 + lr;
            size_t g = ((size_t)(b * TT + row)) * DM + h * HD + kc * 32 + lg * 8;
            kf[rt][kc][0] = __builtin_bit_cast(short8, *(const int4*)&Khi[g]);
            kf[rt][kc][1] = __builtin_bit_cast(short8, *(const int4*)&Klo[g]);
        }

    // prologue: prefetch tile 0 into registers (Q rows permuted)
    int4 qreg[4], vreg[4];
    #pragma unroll
    for (int it = 0; it < 4; ++it) {
        int gi = it * 256 + tid, fr = gi >> 3, ch = gi & 7;
        int qrow = qperm(fr & 63);
        const unsigned short* qsrc = (fr < 64) ? Qhi : Qlo;
        qreg[it] = *(const int4*)&qsrc[((size_t)(b * TT + qrow)) * DM + h * HD + ch * 8];
        const unsigned short* vsrc = (fr < 64) ? Vthi : Vtlo;
        vreg[it] = *(const int4*)&vsrc[((size_t)((b * NH + h) * HD + (fr & 63))) * TT + ch * 8];
    }

    float m_s[2], l_s[2];
    f32x4 oacc[2][4];
    #pragma unroll
    for (int rt = 0; rt < 2; ++rt) {
        m_s[rt] = -INFINITY; l_s[rt] = 0.f;
        #pragma unroll
        for (int dt = 0; dt < 4; ++dt) oacc[rt][dt] = (f32x4){0.f, 0.f, 0.f, 0.f};
    }

    for (int c0 = 0; c0 < TT; c0 += 64) {
        #pragma unroll
        for (int it = 0; it < 4; ++it) {
            int gi = it * 256 + tid, fr = gi >> 3, ch = gi & 7;
            *(int4*)&Qs[fr][ch * 8] = qreg[it];
            *(int4*)&Vs[fr][ch * 8] = vreg[it];
        }
        __syncthreads();

        // prefetch next tile
        int cn = c0 + 64; if (cn >= TT) cn = 0;
        #pragma unroll
        for (int it = 0; it < 4; ++it) {
            int gi = it * 256 + tid, fr = gi >> 3, ch = gi & 7;
            int qrow = cn + qperm(fr & 63);
            const unsigned short* qsrc = (fr < 64) ? Qhi : Qlo;
            qreg[it] = *(const int4*)&qsrc[((size_t)(b * TT + qrow)) * DM + h * HD + ch * 8];
            const unsigned short* vsrc = (fr < 64) ? Vthi : Vtlo;
            vreg[it] = *(const int4*)&vsrc[((size_t)((b * NH + h) * HD + (fr & 63))) * TT + cn + ch * 8];
        }

        // S^T = Q @ K^T (3-term split): sacc[rt][qt] row=q~tile-row, col=krow
        f32x4 sacc[2][4];
        #pragma unroll
        for (int rt = 0; rt < 2; ++rt)
            #pragma unroll
            for (int qt = 0; qt < 4; ++qt) sacc[rt][qt] = (f32x4){0.f, 0.f, 0.f, 0.f};
        __builtin_amdgcn_s_setprio(1);
        #pragma unroll
        for (int kc = 0; kc < 2; ++kc) {
            #pragma unroll
            for (int qt = 0; qt < 4; ++qt) {
                short8 qh = __builtin_bit_cast(short8, *(const int4*)&Qs[qt * 16 + lr][kc * 32 + lg * 8]);
                short8 ql = __builtin_bit_cast(short8, *(const int4*)&Qs[64 + qt * 16 + lr][kc * 32 + lg * 8]);
                #pragma unroll
                for (int rt = 0; rt < 2; ++rt) {
                    sacc[rt][qt] = __builtin_amdgcn_mfma_f32_16x16x32_bf16(qh, kf[rt][kc][0], sacc[rt][qt], 0, 0, 0);
                    sacc[rt][qt] = __builtin_amdgcn_mfma_f32_16x16x32_bf16(ql, kf[rt][kc][0], sacc[rt][qt], 0, 0, 0);
                    sacc[rt][qt] = __builtin_amdgcn_mfma_f32_16x16x32_bf16(qh, kf[rt][kc][1], sacc[rt][qt], 0, 0, 0);
                }
            }
        }
        __builtin_amdgcn_s_setprio(0);

        // online softmax (per-lane: krow = rt*16+lr) + pack P hi/lo in-register
        unsigned int hp[2][4][2], lp[2][4][2];
        float alpha[2];
        #pragma unroll
        for (int rt = 0; rt < 2; ++rt) {
            float mx = -INFINITY;
            #pragma unroll
            for (int qt = 0; qt < 4; ++qt)
                #pragma unroll
                for (int r = 0; r < 4; ++r) mx = fmaxf(mx, sacc[rt][qt][r]);
            mx = fmaxf(mx, __shfl_xor(mx, 16));
            mx = fmaxf(mx, __shfl_xor(mx, 32));
            float nm = fmaxf(m_s[rt], mx);
            float al = __expf(m_s[rt] - nm);
            float sum = 0.f;
            #pragma unroll
            for (int qt = 0; qt < 4; ++qt)
                #pragma unroll
                for (int r = 0; r < 4; ++r) {
                    float p = __expf(sacc[rt][qt][r] - nm);
                    sacc[rt][qt][r] = p;
                    sum += p;
                }
            sum += __shfl_xor(sum, 16);
            sum += __shfl_xor(sum, 32);
            m_s[rt] = nm;
            l_s[rt] = l_s[rt] * al + sum;
            alpha[rt] = al;
            // pack: r-pairs -> u32 of 2 bf16 (these ARE the PV B-frag words)
            #pragma unroll
            for (int qt = 0; qt < 4; ++qt)
                #pragma unroll
                for (int pp = 0; pp < 2; ++pp) {
                    float p0 = sacc[rt][qt][2 * pp];
                    float p1 = sacc[rt][qt][2 * pp + 1];
                    unsigned int u0 = __builtin_bit_cast(unsigned int, p0);
                    unsigned int u1 = __builtin_bit_cast(unsigned int, p1);
                    unsigned int h0 = u0 >> 16, h1 = u1 & 0xFFFF0000u;
                    hp[rt][qt][pp] = h0 | h1;
                    float r0f = p0 - bf2f((unsigned short)h0);
                    float r1f = p1 - bf2f((unsigned short)(u1 >> 16));
                    lp[rt][qt][pp] = (__builtin_bit_cast(unsigned int, r0f) >> 16)
                                   | (__builtin_bit_cast(unsigned int, r1f) & 0xFFFF0000u);
                }
            // rescale accumulated output
            #pragma unroll
            for (int dt = 0; dt < 4; ++dt)
                #pragma unroll
                for (int r = 0; r < 4; ++r) oacc[rt][dt][r] *= al;
        }

        // out^T += V^T @ P (3-term split); V frags shared across rt
        __builtin_amdgcn_s_setprio(1);
        #pragma unroll
        for (int c = 0; c < 2; ++c) {
            short8 pf[2], plf[2];
            #pragma unroll
            for (int rt = 0; rt < 2; ++rt) {
                int4 ph4 = {(int)hp[rt][2 * c][0], (int)hp[rt][2 * c][1],
                            (int)hp[rt][2 * c + 1][0], (int)hp[rt][2 * c + 1][1]};
                int4 pl4 = {(int)lp[rt][2 * c][0], (int)lp[rt][2 * c][1],
                            (int)lp[rt][2 * c + 1][0], (int)lp[rt][2 * c + 1][1]};
                pf[rt]  = __builtin_bit_cast(short8, ph4);
                plf[rt] = __builtin_bit_cast(short8, pl4);
            }
            #pragma unroll
            for (int dt = 0; dt < 4; ++dt) {
                short8 vh = __builtin_bit_cast(short8, *(const int4*)&Vs[dt * 16 + lr][c * 32 + lg * 8]);
                short8 vl = __builtin_bit_cast(short8, *(const int4*)&Vs[64 + dt * 16 + lr][c * 32 + lg * 8]);
                #pragma unroll
                for (int rt = 0; rt < 2; ++rt) {
                    oacc[rt][dt] = __builtin_amdgcn_mfma_f32_16x16x32_bf16(vh, pf[rt],  oacc[rt][dt], 0, 0, 0);
                    oacc[rt][dt] = __builtin_amdgcn_mfma_f32_16x16x32_bf16(vl, pf[rt],  oacc[rt][dt], 0, 0, 0);
                    oacc[rt][dt] = __builtin_amdgcn_mfma_f32_16x16x32_bf16(vh, plf[rt], oacc[rt][dt], 0, 0, 0);
                }
            }
        }
        __builtin_amdgcn_s_setprio(0);
        __syncthreads();
    }

    // epilogue: out[krow][d] = oacc / l  (all lane-local)
    #pragma unroll
    for (int rt = 0; rt < 2; ++rt) {
        float inv = __builtin_amdgcn_rcpf(l_s[rt]);
        int row = wr0 + rt * 16 + lr;
        #pragma unroll
        for (int dt = 0; dt < 4; ++dt)
            #pragma unroll
            for (int r = 0; r < 4; ++r)
                Out[((size_t)(b * TT + row)) * DM + h * HD + dt * 16 + lg * 4 + r] =
                    oacc[rt][dt][r] * inv;
    }
}

// ---------------------------------------------------------------------------
extern "C" void kernel_launch(void* const* d_in, const int* in_sizes, int n_in,
                              void* d_out, int out_size, void* d_ws, size_t ws_size,
                              hipStream_t stream)
{
    const float* x  = (const float*)d_in[0];
    const float* Wk = (const float*)d_in[1];
    const float* bk = (const float*)d_in[2];
    const float* Wq = (const float*)d_in[3];
    const float* bq = (const float*)d_in[4];
    const float* Wv = (const float*)d_in[5];
    const float* bv = (const float*)d_in[6];
    float* out = (float*)d_out;

    const size_t SZ = (size_t)2 * TT * DM;
    unsigned short* Qhi  = (unsigned short*)d_ws;
    unsigned short* Qlo  = Qhi + SZ;
    unsigned short* Khi  = Qlo + SZ;
    unsigned short* Klo  = Khi + SZ;
    unsigned short* Vthi = Klo + SZ;
    unsigned short* Vtlo = Vthi + SZ;
    unsigned short* Whi  = Vtlo + SZ;
    unsigned short* Wlo  = Whi + (size_t)3 * WN;

    wsplit<<<dim3(WN / 2048, 3), dim3(256), 0, stream>>>(Wq, Wk, Wv, Whi, Wlo);

    dim3 pgrid(2 * TT / 128, DM / 64, 3);
    proj_mfma<<<pgrid, dim3(256), 0, stream>>>(x, Whi, Wlo, bq, bk, bv,
                                               Qhi, Qlo, Khi, Klo, Vthi, Vtlo);

    dim3 agrid(TT / 128, NH, 2);
    attn_mfma<<<agrid, dim3(256), 0, stream>>>(Qhi, Qlo, Khi, Klo, Vthi, Vtlo, out);
}